// Round 1
// 251.146 us; speedup vs baseline: 1.0816x; 1.0816x over previous
//
#include <hip/hip_runtime.h>
#include <hip/hip_bf16.h>

typedef short bf16x8 __attribute__((ext_vector_type(8)));
typedef short short4v __attribute__((ext_vector_type(4)));
typedef float f32x4 __attribute__((ext_vector_type(4)));

template <bool V> struct BoolC { static constexpr bool value = V; };

__device__ __forceinline__ short f2b(float f) {
  __hip_bfloat16 h = __float2bfloat16(f);
  union { __hip_bfloat16 h; short s; } u; u.h = h; return u.s;
}

// async 16B global -> LDS DMA (lane i lands at lds_base + i*16; lds ptr wave-uniform)
__device__ __forceinline__ void async_copy16(const short* g, short* l) {
  __builtin_amdgcn_global_load_lds((const __attribute__((address_space(1))) void*)g,
                                   (__attribute__((address_space(3))) void*)l, 16, 0, 0);
}

// ---------------- fused preprocessing: x->bf16, w_attn^T (qscaled), w_proj^T ----------------
// blocks [0,8192): cvt x (f32->bf16, float4/thread)
// blocks [8192,11264): tcvt w_attn -> waT[3072][1024], Q-cols (orow<1024) scaled
// blocks [11264,12288): tcvt w_proj -> wpT[1024][1024]
__global__ __launch_bounds__(256) void pre_kernel(const float* __restrict__ x, short* __restrict__ xb,
                                                  const float* __restrict__ wa, short* __restrict__ waT,
                                                  const float* __restrict__ wp, short* __restrict__ wpT,
                                                  float qscale) {
  const int tid = threadIdx.x;
  const int blk = blockIdx.x;
  if (blk < 8192) {
    const int i = blk * 256 + tid;
    const float4 v = ((const float4*)x)[i];
    short4v o;
    o[0] = f2b(v.x); o[1] = f2b(v.y); o[2] = f2b(v.z); o[3] = f2b(v.w);
    ((short4v*)xb)[i] = o;
    return;
  }
  __shared__ float t[32][33];
  const float* in; short* out;
  int idx, gxb, Cn, qrows; float qs;
  if (blk < 11264) { idx = blk - 8192;  in = wa; out = waT; gxb = 96; Cn = 3072; qrows = 1024; qs = qscale; }
  else             { idx = blk - 11264; in = wp; out = wpT; gxb = 32; Cn = 1024; qrows = 0;    qs = 1.0f; }
  const int bx = idx % gxb, by = idx / gxb;
  const int tx = tid & 31, ty = tid >> 5;
  const int c0 = bx * 32, r0 = by * 32;
#pragma unroll
  for (int yy = 0; yy < 32; yy += 8)
    t[ty + yy][tx] = in[(size_t)(r0 + ty + yy) * Cn + (c0 + tx)];
  __syncthreads();
#pragma unroll
  for (int yy = 0; yy < 32; yy += 8) {
    const int orow = c0 + ty + yy;
    float v = t[tx][ty + yy];
    if (orow < qrows) v *= qs;
    out[(size_t)orow * 1024 + (r0 + tx)] = f2b(v);
  }
}

// ---------------- V transpose: qkv V-block [b][t][h*64+d] -> vT[(b*16+h)*64+d][t] ----------------
__global__ __launch_bounds__(256) void vtrans_kernel(const short* __restrict__ qkv,
                                                     short* __restrict__ vT) {
  constexpr int T = 2048, C3 = 3072, HD = 64;
  const int bh = blockIdx.y, b = bh >> 4, h = bh & 15;
  const int t0 = blockIdx.x * 64;
  __shared__ short tile[64][72];
  const int tid = threadIdx.x;
  const int tr = tid >> 2, dc = (tid & 3) * 16;
  const short* src = qkv + (size_t)b * T * C3 + (size_t)(t0 + tr) * C3 + 2048 + h * HD + dc;
  *(bf16x8*)&tile[tr][dc] = *(const bf16x8*)src;
  *(bf16x8*)&tile[tr][dc + 8] = *(const bf16x8*)(src + 8);
  __syncthreads();
  const int dr = tid >> 2, tc = (tid & 3) * 16;
  bf16x8 o0, o1;
#pragma unroll
  for (int i = 0; i < 8; i++) o0[i] = tile[tc + i][dr];
#pragma unroll
  for (int i = 0; i < 8; i++) o1[i] = tile[tc + 8 + i][dr];
  short* dst = vT + ((size_t)bh * HD + dr) * T + t0 + tc;
  *(bf16x8*)dst = o0;
  *(bf16x8*)(dst + 8) = o1;
}

// ---------------- C[M,N] = A[M,K] * Bt[N,K]^T — 256xBN tile, 4-phase/K-tile pipeline ----------------
// 512 threads = 8 waves (2 M-halves x 4 N-quarters); per-wave output 128 x (BN/4).
// BK=64, double-buffered LDS. A stored quadrant-major [q][half][32r][64k] so phase p
// consumes exactly A-chunk p; B plain [BN][64]. Both XOR-swizzled per 16B chunk
// (chunk ^= row&7) via inverse-swizzled per-lane GLOBAL addresses (LDS dest linear,
// required by global_load_lds). Stage stream per K-tile (per wave, order fixed):
// B0..B(NB-1),A0..A3 for tile t+1, 2 instr/phase, issued into buf^1 (never races the
// buffer being read). Counted vmcnt guards before each phase's barrier force exactly
// the chunks that phase reads (per-wave in-order retirement ledger):
// steady {3,4,5,6}; peeled last tile {3,2,1,0}. Never vmcnt(0) in the main loop.
template <int BN, typename OutT>
__global__ __launch_bounds__(512, 2) void gemm8p_kernel(const short* __restrict__ A,
                                                        const short* __restrict__ Bt,
                                                        OutT* __restrict__ C,
                                                        int M, int N, int K) {
  constexpr int NB = BN / 64;        // B chunks per K-tile == n-frags per wave
  constexpr int NSTREAM = NB + 4;    // loads per tile per wave
  __shared__ short ldsA[2][16384];
  __shared__ short ldsB[2][NB * 4096];

  const int tid = threadIdx.x;
  const int w = tid >> 6, lane = tid & 63;
  const int quad = lane >> 4, l16 = lane & 15;
  const int half = w >> 2;
  const int wn = (w & 3) * (BN / 4);
  const int wm = half * 128;

  // XCD-aware bijective swizzle (grid block count divisible by 8)
  const int gx = gridDim.x;
  const int nwg = gx * gridDim.y;
  const int flat = blockIdx.y * gx + blockIdx.x;
  const int swz = (flat & 7) * (nwg >> 3) + (flat >> 3);
  const int bn = swz % gx, bm = swz / gx;
  const int m0 = bm * 256, n0 = bn * BN;

  // staging sources: lane covers 16B at (row, phys_chunk=lane&7); data for logical
  // chunk cl = (lane&7) ^ (row&7) -> coalesced (full 128B row per 8 lanes)
  const int rsub = lane >> 3;                 // 0..7
  const int cl = (lane & 7) ^ rsub;           // logical 16B chunk
  const short* pAsrc = A + (size_t)(m0 + half * 128 + (w & 3) * 8 + rsub) * K + cl * 8;
  const short* pBsrc = Bt + (size_t)(n0 + w * 8 + rsub) * K + cl * 8;
  const int dstoff = w * 512;                 // shorts: wave slice within 8KB chunk

  f32x4 acc[8][NB] = {};
  bf16x8 bfr[NB][2];

  auto issue = [&](int i, int buf, int tt) {
    if (i < NB)
      async_copy16(pBsrc + (size_t)(i * 64) * K + tt * 64, &ldsB[buf][i * 4096 + dstoff]);
    else
      async_copy16(pAsrc + (size_t)((i - NB) * 32) * K + tt * 64,
                   &ldsA[buf][(i - NB) * 4096 + dstoff]);
  };

  // prologue: stage tile 0 into buf 0 (same stream order as steady state)
#pragma unroll
  for (int i = 0; i < NSTREAM; ++i) issue(i, 0, 0);

  const int NT = K >> 6;

#define GEMM_PHASE(P, GS, GL)                                                                  \
  {                                                                                            \
    if constexpr (LAST) { asm volatile("s_waitcnt vmcnt(" #GL ")" ::: "memory"); }             \
    else                { asm volatile("s_waitcnt vmcnt(" #GS ")" ::: "memory"); }             \
    __builtin_amdgcn_s_barrier();                                                              \
    asm volatile("" ::: "memory");                                                             \
    bf16x8 af[2][2];                                                                           \
    _Pragma("unroll") for (int mm = 0; mm < 2; ++mm)                                           \
    _Pragma("unroll") for (int kh = 0; kh < 2; ++kh)                                           \
      af[mm][kh] = *(const bf16x8*)&ldsA[buf][((P * 2 + half) * 32 + mm * 16 + l16) * 64 +     \
                                              (((kh * 4 + quad) ^ (l16 & 7)) * 8)];            \
    if constexpr (P == 0) {                                                                    \
      _Pragma("unroll") for (int nf = 0; nf < NB; ++nf)                                        \
      _Pragma("unroll") for (int kh = 0; kh < 2; ++kh)                                         \
        bfr[nf][kh] = *(const bf16x8*)&ldsB[buf][(wn + nf * 16 + l16) * 64 +                   \
                                                 (((kh * 4 + quad) ^ (l16 & 7)) * 8)];         \
    }                                                                                          \
    if constexpr (!LAST) {                                                                     \
      if constexpr (2 * P < NSTREAM) issue(2 * P, buf ^ 1, t + 1);                             \
      if constexpr (2 * P + 1 < NSTREAM) issue(2 * P + 1, buf ^ 1, t + 1);                     \
    }                                                                                          \
    __builtin_amdgcn_s_setprio(1);                                                             \
    _Pragma("unroll") for (int mm = 0; mm < 2; ++mm)                                           \
    _Pragma("unroll") for (int nf = 0; nf < NB; ++nf) {                                        \
      acc[P * 2 + mm][nf] = __builtin_amdgcn_mfma_f32_16x16x32_bf16(af[mm][0], bfr[nf][0],     \
                                                                    acc[P * 2 + mm][nf], 0, 0, 0); \
      acc[P * 2 + mm][nf] = __builtin_amdgcn_mfma_f32_16x16x32_bf16(af[mm][1], bfr[nf][1],     \
                                                                    acc[P * 2 + mm][nf], 0, 0, 0); \
    }                                                                                          \
    __builtin_amdgcn_s_setprio(0);                                                             \
    __builtin_amdgcn_s_barrier();                                                              \
  }

  auto tile = [&](int t, auto lastc) {
    constexpr bool LAST = decltype(lastc)::value;
    const int buf = t & 1;
    GEMM_PHASE(0, 3, 3)
    GEMM_PHASE(1, 4, 2)
    GEMM_PHASE(2, 5, 1)
    GEMM_PHASE(3, 6, 0)
  };

  for (int t = 0; t < NT - 1; ++t) tile(t, BoolC<false>{});
  tile(NT - 1, BoolC<true>{});
#undef GEMM_PHASE

  (void)M;
#pragma unroll
  for (int mf = 0; mf < 8; ++mf)
#pragma unroll
    for (int nf = 0; nf < NB; ++nf) {
      const int col = n0 + wn + nf * 16 + l16;
#pragma unroll
      for (int r = 0; r < 4; ++r) {
        const int row = m0 + wm + mf * 16 + quad * 4 + r;
        if constexpr (sizeof(OutT) == 4)
          C[(size_t)row * N + col] = acc[mf][nf][r];
        else
          C[(size_t)row * N + col] = f2b(acc[mf][nf][r]);
      }
    }
}

// ---------------- causal flash attention: 128-row Q-tiles, DMA double-buffer ----------------
// grid (8, B*H), block 256 = 4 waves; block x handles 128-row qtiles {15-x, x}.
// Per wave: 32 q-rows (two 16-row subtiles) sharing one K/V fragment set per iter.
// Fixed-base softmax (bounded logits -> p=exp2(s) exactly, partials additive).
// ONE barrier per iter: global_load_lds DMA for tile j+1 into buf[cur^1] is issued
// right after the barrier; the NEXT iteration's barrier (implicit vmcnt(0)) drains
// it after a full compute section — latency hidden, no VGPRs held. DMA forbids padded
// LDS, so Ks/Vt are unpadded stride-64 with XOR swizzle: row r, 16B-chunk c stored at
// chunk c^(r&7). Per-lane *global* addresses are permuted to produce this.
__global__ __launch_bounds__(256, 2) void attn_kernel(const short* __restrict__ qkv,
                                                      const short* __restrict__ vT,
                                                      short* __restrict__ y) {
  constexpr int T = 2048, C3 = 3072, Cc = 1024, HD = 64;
  const int bh = blockIdx.y, b = bh >> 4, h = bh & 15;
  const int tid = threadIdx.x, lane = tid & 63, wave = tid >> 6;
  const int quad = lane >> 4, l16 = lane & 15;

  __shared__ short Ksb[2][64 * 64];    // [buf][kv][d], XOR-swizzled chunks
  __shared__ short Vtb[2][64 * 64];    // [buf][d][kv], XOR-swizzled chunks
  __shared__ short Ps[4][2][16 * 68];  // per-wave, per-subtile P [q][kv], padded

  const size_t base = (size_t)b * T * C3;
  const int qcol = h * HD, kcol = Cc + h * HD;
  const size_t vtbase = (size_t)bh * HD * T;

  const int r8 = lane >> 3;
  const int cg8 = ((lane & 7) ^ r8) * 8;
  const short* gk[2];
  const short* gv[2];
  short* lk[2][2]; short* lv[2][2];
#pragma unroll
  for (int t8 = 0; t8 < 2; t8++) {
    const int row = wave * 16 + t8 * 8 + r8;
    gk[t8] = qkv + base + (size_t)row * C3 + kcol + cg8;
    gv[t8] = vT + vtbase + (size_t)row * T + cg8;
#pragma unroll
    for (int bu = 0; bu < 2; bu++) {
      lk[bu][t8] = &Ksb[bu][(wave * 16 + t8 * 8) * 64];
      lv[bu][t8] = &Vtb[bu][(wave * 16 + t8 * 8) * 64];
    }
  }
  const int sw0 = ((quad) ^ (l16 & 7)) * 8;
  const int sw1 = ((quad + 4) ^ (l16 & 7)) * 8;

  bf16x8 ones;
#pragma unroll
  for (int i = 0; i < 8; i++) ones[i] = (short)0x3F80;  // bf16 1.0

  for (int half = 0; half < 2; half++) {
    const int t = half ? blockIdx.x : (15 - blockIdx.x);
    const int q0 = t * 128;
    const int jmax = 2 * t + 1;

    bf16x8 qf[2][2];
#pragma unroll
    for (int s = 0; s < 2; s++) {
      const short* qp = qkv + base + (size_t)(q0 + s * 64 + wave * 16 + l16) * C3 + qcol + quad * 8;
      qf[s][0] = *(const bf16x8*)qp;
      qf[s][1] = *(const bf16x8*)(qp + 32);
    }

    f32x4 o[2][4] = {};
    f32x4 l[2] = {};

    async_copy16(gk[0], lk[0][0]);
    async_copy16(gk[1], lk[0][1]);
    async_copy16(gv[0], lv[0][0]);
    async_copy16(gv[1], lv[0][1]);

    for (int j = 0; j <= jmax; j++) {
      const int cur = j & 1;
      __syncthreads();  // drains vmcnt: tile j staged in buf[cur]

      if (j < jmax) {
        const size_t ko = (size_t)(j + 1) * 64 * C3;
        const int vo = (j + 1) * 64;
        async_copy16(gk[0] + ko, lk[cur ^ 1][0]);
        async_copy16(gk[1] + ko, lk[cur ^ 1][1]);
        async_copy16(gv[0] + vo, lv[cur ^ 1][0]);
        async_copy16(gv[1] + vo, lv[cur ^ 1][1]);
      }

      bf16x8 kf[4][2], vf[4][2];
#pragma unroll
      for (int nt = 0; nt < 4; nt++) {
        const int rowb = (nt * 16 + l16) * 64;
        kf[nt][0] = *(const bf16x8*)&Ksb[cur][rowb + sw0];
        kf[nt][1] = *(const bf16x8*)&Ksb[cur][rowb + sw1];
        vf[nt][0] = *(const bf16x8*)&Vtb[cur][rowb + sw0];
        vf[nt][1] = *(const bf16x8*)&Vtb[cur][rowb + sw1];
      }

      const bool lo_act = (j < jmax);

#pragma unroll
      for (int s = 0; s < 2; s++) {
        if (s == 0 && !lo_act) continue;
        f32x4 sc[4];
#pragma unroll
        for (int nt = 0; nt < 4; nt++) {
          f32x4 a = {};
          a = __builtin_amdgcn_mfma_f32_16x16x32_bf16(qf[s][0], kf[nt][0], a, 0, 0, 0);
          a = __builtin_amdgcn_mfma_f32_16x16x32_bf16(qf[s][1], kf[nt][1], a, 0, 0, 0);
          sc[nt] = a;
        }
        const bool diag = (s == 0) ? (j == jmax - 1) : (j == jmax);
        if (diag) {
#pragma unroll
          for (int nt = 0; nt < 4; nt++)
#pragma unroll
            for (int r = 0; r < 4; r++) {
              const int row_l = wave * 16 + quad * 4 + r;
              const int col_l = nt * 16 + l16;
              if (col_l > row_l) sc[nt][r] = -INFINITY;
            }
        }
#pragma unroll
        for (int nt = 0; nt < 4; nt++)
#pragma unroll
          for (int r = 0; r < 4; r++)
            Ps[wave][s][(quad * 4 + r) * 68 + nt * 16 + l16] =
                f2b(__builtin_amdgcn_exp2f(sc[nt][r]));
      }
      asm volatile("s_waitcnt lgkmcnt(0)" ::: "memory");

#pragma unroll
      for (int s = 0; s < 2; s++) {
        if (s == 0 && !lo_act) continue;
        bf16x8 pa0 = *(const bf16x8*)&Ps[wave][s][l16 * 68 + quad * 8];
        bf16x8 pa1 = *(const bf16x8*)&Ps[wave][s][l16 * 68 + 32 + quad * 8];
        f32x4 lsum = {};
        lsum = __builtin_amdgcn_mfma_f32_16x16x32_bf16(pa0, ones, lsum, 0, 0, 0);
        lsum = __builtin_amdgcn_mfma_f32_16x16x32_bf16(pa1, ones, lsum, 0, 0, 0);
        l[s] += lsum;
#pragma unroll
        for (int nt = 0; nt < 4; nt++) {
          o[s][nt] = __builtin_amdgcn_mfma_f32_16x16x32_bf16(pa0, vf[nt][0], o[s][nt], 0, 0, 0);
          o[s][nt] = __builtin_amdgcn_mfma_f32_16x16x32_bf16(pa1, vf[nt][1], o[s][nt], 0, 0, 0);
        }
      }
    }

#pragma unroll
    for (int s = 0; s < 2; s++)
#pragma unroll
      for (int nt = 0; nt < 4; nt++)
#pragma unroll
        for (int r = 0; r < 4; r++) {
          const int row_g = q0 + s * 64 + wave * 16 + quad * 4 + r;
          y[(size_t)(b * T + row_g) * Cc + h * HD + nt * 16 + l16] = f2b(o[s][nt][r] / l[s][r]);
        }
  }
}

extern "C" void kernel_launch(void* const* d_in, const int* in_sizes, int n_in,
                              void* d_out, int out_size, void* d_ws, size_t ws_size,
                              hipStream_t stream) {
  constexpr int B = 4, T = 2048, C = 1024;
  constexpr int M = B * T;          // 8192
  constexpr int N1 = 3 * C;         // 3072
  const float* x      = (const float*)d_in[0];
  const float* w_attn = (const float*)d_in[1];
  const float* w_proj = (const float*)d_in[2];
  float* out = (float*)d_out;

  char* ws = (char*)d_ws;
  short* xb   = (short*)(ws + 0);                       // 16 MB (x bf16; reused as vT)
  short* waT  = (short*)(ws + 16777216);                // 6 MB
  short* wpT  = (short*)(ws + 23068672);                // 2 MB
  short* qkvb = (short*)(ws + 25165824);                // 48 MB
  short* yb   = (short*)(ws + 75497472);                // 16 MB
  short* vT   = xb;                                     // xb dead after qkv GEMM

  const float qscale = 0.125f * 1.44269504088896340736f;  // 1/sqrt(64) * log2(e)

  // fused preprocessing: 8192 cvt blocks + 3072 waT blocks + 1024 wpT blocks
  pre_kernel<<<12288, 256, 0, stream>>>(x, xb, w_attn, waT, w_proj, wpT, qscale);
  // qkv: 256x192 tile -> 16x32 = 512 blocks = 2 full CU-waves
  gemm8p_kernel<192, short><<<dim3(N1 / 192, M / 256), 512, 0, stream>>>(xb, waT, qkvb, M, N1, C);
  vtrans_kernel<<<dim3(T / 64, B * 16), 256, 0, stream>>>(qkvb, vT);
  attn_kernel<<<dim3(8, B * 16), 256, 0, stream>>>(qkvb, vT, yb);
  // proj: 256x128 tile -> 8x32 = 256 blocks = exactly 1 CU-wave
  gemm8p_kernel<128, float><<<dim3(C / 128, M / 256), 512, 0, stream>>>(yb, wpT, out, M, C, C);
}

// Round 2
// 229.182 us; speedup vs baseline: 1.1852x; 1.0958x over previous
//
#include <hip/hip_runtime.h>
#include <hip/hip_bf16.h>

typedef short bf16x8 __attribute__((ext_vector_type(8)));
typedef short short4v __attribute__((ext_vector_type(4)));
typedef float f32x4 __attribute__((ext_vector_type(4)));
typedef float f32x16 __attribute__((ext_vector_type(16)));

template <bool V> struct BoolC { static constexpr bool value = V; };

__device__ __forceinline__ short f2b(float f) {
  __hip_bfloat16 h = __float2bfloat16(f);
  union { __hip_bfloat16 h; short s; } u; u.h = h; return u.s;
}

// packed f32->bf16 pair (RNE), low = lo, high = hi
__device__ __forceinline__ unsigned cvtpk_bf16(float lo, float hi) {
  unsigned r;
  asm("v_cvt_pk_bf16_f32 %0, %1, %2" : "=v"(r) : "v"(lo), "v"(hi));
  return r;
}

__device__ __forceinline__ f32x16 mfma32(bf16x8 a, bf16x8 b, f32x16 c) {
  return __builtin_amdgcn_mfma_f32_32x32x16_bf16(a, b, c, 0, 0, 0);
}

// async 16B global -> LDS DMA (lane i lands at lds_base + i*16; lds ptr wave-uniform)
__device__ __forceinline__ void async_copy16(const short* g, short* l) {
  __builtin_amdgcn_global_load_lds((const __attribute__((address_space(1))) void*)g,
                                   (__attribute__((address_space(3))) void*)l, 16, 0, 0);
}

// ---------------- fused preprocessing: x->bf16, w_attn^T (qscaled), w_proj^T ----------------
__global__ __launch_bounds__(256) void pre_kernel(const float* __restrict__ x, short* __restrict__ xb,
                                                  const float* __restrict__ wa, short* __restrict__ waT,
                                                  const float* __restrict__ wp, short* __restrict__ wpT,
                                                  float qscale) {
  const int tid = threadIdx.x;
  const int blk = blockIdx.x;
  if (blk < 8192) {
    const int i = blk * 256 + tid;
    const float4 v = ((const float4*)x)[i];
    short4v o;
    o[0] = f2b(v.x); o[1] = f2b(v.y); o[2] = f2b(v.z); o[3] = f2b(v.w);
    ((short4v*)xb)[i] = o;
    return;
  }
  __shared__ float t[32][33];
  const float* in; short* out;
  int idx, gxb, Cn, qrows; float qs;
  if (blk < 11264) { idx = blk - 8192;  in = wa; out = waT; gxb = 96; Cn = 3072; qrows = 1024; qs = qscale; }
  else             { idx = blk - 11264; in = wp; out = wpT; gxb = 32; Cn = 1024; qrows = 0;    qs = 1.0f; }
  const int bx = idx % gxb, by = idx / gxb;
  const int tx = tid & 31, ty = tid >> 5;
  const int c0 = bx * 32, r0 = by * 32;
#pragma unroll
  for (int yy = 0; yy < 32; yy += 8)
    t[ty + yy][tx] = in[(size_t)(r0 + ty + yy) * Cn + (c0 + tx)];
  __syncthreads();
#pragma unroll
  for (int yy = 0; yy < 32; yy += 8) {
    const int orow = c0 + ty + yy;
    float v = t[tx][ty + yy];
    if (orow < qrows) v *= qs;
    out[(size_t)orow * 1024 + (r0 + tx)] = f2b(v);
  }
}

// ---------------- V transpose: qkv V-block [b][t][h*64+d] -> vT[(b*16+h)*64+d][t] ----------------
__global__ __launch_bounds__(256) void vtrans_kernel(const short* __restrict__ qkv,
                                                     short* __restrict__ vT) {
  constexpr int T = 2048, C3 = 3072, HD = 64;
  const int bh = blockIdx.y, b = bh >> 4, h = bh & 15;
  const int t0 = blockIdx.x * 64;
  __shared__ short tile[64][72];
  const int tid = threadIdx.x;
  const int tr = tid >> 2, dc = (tid & 3) * 16;
  const short* src = qkv + (size_t)b * T * C3 + (size_t)(t0 + tr) * C3 + 2048 + h * HD + dc;
  *(bf16x8*)&tile[tr][dc] = *(const bf16x8*)src;
  *(bf16x8*)&tile[tr][dc + 8] = *(const bf16x8*)(src + 8);
  __syncthreads();
  const int dr = tid >> 2, tc = (tid & 3) * 16;
  bf16x8 o0, o1;
#pragma unroll
  for (int i = 0; i < 8; i++) o0[i] = tile[tc + i][dr];
#pragma unroll
  for (int i = 0; i < 8; i++) o1[i] = tile[tc + 8 + i][dr];
  short* dst = vT + ((size_t)bh * HD + dr) * T + t0 + tc;
  *(bf16x8*)dst = o0;
  *(bf16x8*)(dst + 8) = o1;
}

// ---------------- C[M,N] = A[M,K] * Bt[N,K]^T — 256xBN tile, 4-phase/K-tile pipeline ----------------
template <int BN, typename OutT>
__global__ __launch_bounds__(512, 2) void gemm8p_kernel(const short* __restrict__ A,
                                                        const short* __restrict__ Bt,
                                                        OutT* __restrict__ C,
                                                        int M, int N, int K) {
  constexpr int NB = BN / 64;        // B chunks per K-tile == n-frags per wave
  constexpr int NSTREAM = NB + 4;    // loads per tile per wave
  __shared__ short ldsA[2][16384];
  __shared__ short ldsB[2][NB * 4096];

  const int tid = threadIdx.x;
  const int w = tid >> 6, lane = tid & 63;
  const int quad = lane >> 4, l16 = lane & 15;
  const int half = w >> 2;
  const int wn = (w & 3) * (BN / 4);
  const int wm = half * 128;

  const int gx = gridDim.x;
  const int nwg = gx * gridDim.y;
  const int flat = blockIdx.y * gx + blockIdx.x;
  const int swz = (flat & 7) * (nwg >> 3) + (flat >> 3);
  const int bn = swz % gx, bm = swz / gx;
  const int m0 = bm * 256, n0 = bn * BN;

  const int rsub = lane >> 3;                 // 0..7
  const int cl = (lane & 7) ^ rsub;           // logical 16B chunk
  const short* pAsrc = A + (size_t)(m0 + half * 128 + (w & 3) * 8 + rsub) * K + cl * 8;
  const short* pBsrc = Bt + (size_t)(n0 + w * 8 + rsub) * K + cl * 8;
  const int dstoff = w * 512;                 // shorts: wave slice within 8KB chunk

  f32x4 acc[8][NB] = {};
  bf16x8 bfr[NB][2];

  auto issue = [&](int i, int buf, int tt) {
    if (i < NB)
      async_copy16(pBsrc + (size_t)(i * 64) * K + tt * 64, &ldsB[buf][i * 4096 + dstoff]);
    else
      async_copy16(pAsrc + (size_t)((i - NB) * 32) * K + tt * 64,
                   &ldsA[buf][(i - NB) * 4096 + dstoff]);
  };

#pragma unroll
  for (int i = 0; i < NSTREAM; ++i) issue(i, 0, 0);

  const int NT = K >> 6;

#define GEMM_PHASE(P, GS, GL)                                                                  \
  {                                                                                            \
    if constexpr (LAST) { asm volatile("s_waitcnt vmcnt(" #GL ")" ::: "memory"); }             \
    else                { asm volatile("s_waitcnt vmcnt(" #GS ")" ::: "memory"); }             \
    __builtin_amdgcn_s_barrier();                                                              \
    asm volatile("" ::: "memory");                                                             \
    bf16x8 af[2][2];                                                                           \
    _Pragma("unroll") for (int mm = 0; mm < 2; ++mm)                                           \
    _Pragma("unroll") for (int kh = 0; kh < 2; ++kh)                                           \
      af[mm][kh] = *(const bf16x8*)&ldsA[buf][((P * 2 + half) * 32 + mm * 16 + l16) * 64 +     \
                                              (((kh * 4 + quad) ^ (l16 & 7)) * 8)];            \
    if constexpr (P == 0) {                                                                    \
      _Pragma("unroll") for (int nf = 0; nf < NB; ++nf)                                        \
      _Pragma("unroll") for (int kh = 0; kh < 2; ++kh)                                         \
        bfr[nf][kh] = *(const bf16x8*)&ldsB[buf][(wn + nf * 16 + l16) * 64 +                   \
                                                 (((kh * 4 + quad) ^ (l16 & 7)) * 8)];         \
    }                                                                                          \
    if constexpr (!LAST) {                                                                     \
      if constexpr (2 * P < NSTREAM) issue(2 * P, buf ^ 1, t + 1);                             \
      if constexpr (2 * P + 1 < NSTREAM) issue(2 * P + 1, buf ^ 1, t + 1);                     \
    }                                                                                          \
    __builtin_amdgcn_s_setprio(1);                                                             \
    _Pragma("unroll") for (int mm = 0; mm < 2; ++mm)                                           \
    _Pragma("unroll") for (int nf = 0; nf < NB; ++nf) {                                        \
      acc[P * 2 + mm][nf] = __builtin_amdgcn_mfma_f32_16x16x32_bf16(af[mm][0], bfr[nf][0],     \
                                                                    acc[P * 2 + mm][nf], 0, 0, 0); \
      acc[P * 2 + mm][nf] = __builtin_amdgcn_mfma_f32_16x16x32_bf16(af[mm][1], bfr[nf][1],     \
                                                                    acc[P * 2 + mm][nf], 0, 0, 0); \
    }                                                                                          \
    __builtin_amdgcn_s_setprio(0);                                                             \
    __builtin_amdgcn_s_barrier();                                                              \
  }

  auto tile = [&](int t, auto lastc) {
    constexpr bool LAST = decltype(lastc)::value;
    const int buf = t & 1;
    GEMM_PHASE(0, 3, 3)
    GEMM_PHASE(1, 4, 2)
    GEMM_PHASE(2, 5, 1)
    GEMM_PHASE(3, 6, 0)
  };

  for (int t = 0; t < NT - 1; ++t) tile(t, BoolC<false>{});
  tile(NT - 1, BoolC<true>{});
#undef GEMM_PHASE

  (void)M;
#pragma unroll
  for (int mf = 0; mf < 8; ++mf)
#pragma unroll
    for (int nf = 0; nf < NB; ++nf) {
      const int col = n0 + wn + nf * 16 + l16;
#pragma unroll
      for (int r = 0; r < 4; ++r) {
        const int row = m0 + wm + mf * 16 + quad * 4 + r;
        if constexpr (sizeof(OutT) == 4)
          C[(size_t)row * N + col] = acc[mf][nf][r];
        else
          C[(size_t)row * N + col] = f2b(acc[mf][nf][r]);
      }
    }
}

// ---------------- causal flash attention: 32x32 swapped-QK^T, in-register softmax ----------------
// grid (8, B*H) remapped so all 8 q-blocks of a head share one XCD (K+V=512KB/head; 8 heads
// per XCD ~= 4MB L2). Block = 4 waves x 32 q-rows = 128-row qtile; block xb handles qtiles
// {15-xb, xb} (balanced 36 iters). Per KV-tile (64): S^T = mfma32(K, Q) puts col=q=lane&31 —
// each lane owns a full P row slice in regs. exp2 in-place; P->bf16 A-frags via
// v_cvt_pk_bf16_f32 pairs + v_permlane32_swap_b32 (no LDS round-trip, T12). l kept in
// C-layout via ones-MFMA. K/V LDS tiles XOR-chunk-swizzled via permuted DMA source addrs
// (dest must stay linear). Fixed-base softmax (bounded logits), diag iters mask per-reg;
// waves skip the fully-masked upper-kv half (up guard).
__global__ __launch_bounds__(256, 2) void attn_kernel(const short* __restrict__ qkv,
                                                      const short* __restrict__ vT,
                                                      short* __restrict__ y) {
  constexpr int T = 2048, C3 = 3072, Cc = 1024, HD = 64;
  // XCD-aware remap: f = by*8+bx dispatch order; XCD ~= f&7. Same-head blocks get same f&7.
  const int f = blockIdx.y * 8 + blockIdx.x;
  const int bh = (f & 7) * 8 + ((f >> 3) & 7);
  const int xb = f >> 6;
  const int b = bh >> 4, h = bh & 15;
  const int tid = threadIdx.x, lane = tid & 63, wave = tid >> 6;
  const int l32 = lane & 31, hi = lane >> 5;

  __shared__ short Ksb[2][64 * 64];    // [buf][kv][d], XOR-swizzled 16B chunks
  __shared__ short Vtb[2][64 * 64];    // [buf][d][kv], XOR-swizzled 16B chunks

  const size_t base = (size_t)b * T * C3;
  const int qcol = h * HD, kcol = Cc + h * HD;
  const size_t vtbase = (size_t)bh * HD * T;

  // DMA: lane i covers tile row (slab + i>>3), global chunk (i&7)^(i>>3); LDS linear.
  const int r8 = lane >> 3;
  const int cg8 = ((lane & 7) ^ r8) * 8;
  const short* gk[2];
  const short* gv[2];
  short* lk[2][2]; short* lv[2][2];
#pragma unroll
  for (int t8 = 0; t8 < 2; t8++) {
    const int row = wave * 16 + t8 * 8 + r8;
    gk[t8] = qkv + base + (size_t)row * C3 + kcol + cg8;
    gv[t8] = vT + vtbase + (size_t)row * T + cg8;
#pragma unroll
    for (int bu = 0; bu < 2; bu++) {
      lk[bu][t8] = &Ksb[bu][(wave * 16 + t8 * 8) * 64];
      lv[bu][t8] = &Vtb[bu][(wave * 16 + t8 * 8) * 64];
    }
  }
  const int rs7 = l32 & 7;  // frag-read row parity for chunk XOR

  bf16x8 ones;
#pragma unroll
  for (int i = 0; i < 8; i++) ones[i] = (short)0x3F80;  // bf16 1.0

  for (int half = 0; half < 2; half++) {
    const int t = half ? xb : (15 - xb);
    const int q0 = t * 128;
    const int jmax = 2 * t + 1;
    const int jd = 2 * t + (wave >> 1);       // this wave's diagonal KV-tile
    const int qrow = q0 + wave * 32 + l32;    // this lane's q (S^T col)

    // Q B-frags: lane provides B[k=hi*8+j][n=q]: 4 k-windows of 16
    bf16x8 qf[4];
    {
      const short* qp = qkv + base + (size_t)qrow * C3 + qcol + hi * 8;
#pragma unroll
      for (int wk = 0; wk < 4; wk++) qf[wk] = *(const bf16x8*)(qp + wk * 16);
    }

    f32x16 o0 = {}, o1 = {}, lC = {};

    // prologue DMA tile 0 -> buf 0 (drained by first barrier)
    async_copy16(gk[0], lk[0][0]);
    async_copy16(gk[1], lk[0][1]);
    async_copy16(gv[0], lv[0][0]);
    async_copy16(gv[1], lv[0][1]);

    for (int j = 0; j <= jmax; j++) {
      const int cur = j & 1;
      __syncthreads();  // drains vmcnt: tile j staged in buf[cur]

      if (j < jmax) {
        const size_t ko = (size_t)(j + 1) * 64 * C3;
        const int vo = (j + 1) * 64;
        async_copy16(gk[0] + ko, lk[cur ^ 1][0]);
        async_copy16(gk[1] + ko, lk[cur ^ 1][1]);
        async_copy16(gv[0] + vo, lv[cur ^ 1][0]);
        async_copy16(gv[1] + vo, lv[cur ^ 1][1]);
      }

      if (j > jd) continue;  // fully-masked tile for this wave (barriers above still uniform)

      // upper-kv half (kv 32..63 of this tile) has any unmasked element?
      const bool up = (64 * j + 32) <= (q0 + wave * 32 + 31);

      // ---- QK^T (swapped): st = K-tile x Q^T, col=q, row=kv ----
      f32x16 st0 = {}, st1 = {};
      __builtin_amdgcn_s_setprio(1);
#pragma unroll
      for (int wk = 0; wk < 4; wk++) {
        const bf16x8 k0 = *(const bf16x8*)&Ksb[cur][l32 * 64 + (((2 * wk + hi) ^ rs7) * 8)];
        st0 = mfma32(k0, qf[wk], st0);
      }
      if (up) {
#pragma unroll
        for (int wk = 0; wk < 4; wk++) {
          const bf16x8 k1 = *(const bf16x8*)&Ksb[cur][(32 + l32) * 64 + (((2 * wk + hi) ^ rs7) * 8)];
          st1 = mfma32(k1, qf[wk], st1);
        }
      }
      __builtin_amdgcn_s_setprio(0);

      // ---- causal mask on diagonal tile ----
      if (j == jd) {
#pragma unroll
        for (int r = 0; r < 16; r++) {
          const int kvl = 64 * j + (r & 3) + 8 * (r >> 2) + 4 * hi;
          if (kvl > qrow) st0[r] = -INFINITY;
          if (up && (kvl + 32 > qrow)) st1[r] = -INFINITY;
        }
      }

      // ---- V B-frags (kv-windows 0,1 always; 2,3 only if up) ----
      bf16x8 vf00, vf01, vf10, vf11, vf02, vf03, vf12, vf13;
      vf00 = *(const bf16x8*)&Vtb[cur][l32 * 64 + (((0 + hi) ^ rs7) * 8)];
      vf01 = *(const bf16x8*)&Vtb[cur][l32 * 64 + (((2 + hi) ^ rs7) * 8)];
      vf10 = *(const bf16x8*)&Vtb[cur][(32 + l32) * 64 + (((0 + hi) ^ rs7) * 8)];
      vf11 = *(const bf16x8*)&Vtb[cur][(32 + l32) * 64 + (((2 + hi) ^ rs7) * 8)];
      if (up) {
        vf02 = *(const bf16x8*)&Vtb[cur][l32 * 64 + (((4 + hi) ^ rs7) * 8)];
        vf03 = *(const bf16x8*)&Vtb[cur][l32 * 64 + (((6 + hi) ^ rs7) * 8)];
        vf12 = *(const bf16x8*)&Vtb[cur][(32 + l32) * 64 + (((4 + hi) ^ rs7) * 8)];
        vf13 = *(const bf16x8*)&Vtb[cur][(32 + l32) * 64 + (((6 + hi) ^ rs7) * 8)];
      }

      // ---- exp2 in-place, pack P->bf16 A-frags via cvt_pk + permlane32_swap ----
#pragma unroll
      for (int r = 0; r < 16; r++) st0[r] = __builtin_amdgcn_exp2f(st0[r]);
      bf16x8 pa0, pa1, pa2, pa3;
      {
        unsigned a0 = cvtpk_bf16(st0[0], st0[1]), c0 = cvtpk_bf16(st0[2], st0[3]);
        unsigned b0 = cvtpk_bf16(st0[4], st0[5]), d0 = cvtpk_bf16(st0[6], st0[7]);
        asm volatile("v_permlane32_swap_b32 %0, %1" : "+v"(a0), "+v"(b0));
        asm volatile("v_permlane32_swap_b32 %0, %1" : "+v"(c0), "+v"(d0));
        union { unsigned u[4]; bf16x8 v; } p; p.u[0] = a0; p.u[1] = c0; p.u[2] = b0; p.u[3] = d0;
        pa0 = p.v;
        unsigned a1 = cvtpk_bf16(st0[8], st0[9]), c1 = cvtpk_bf16(st0[10], st0[11]);
        unsigned b1 = cvtpk_bf16(st0[12], st0[13]), d1 = cvtpk_bf16(st0[14], st0[15]);
        asm volatile("v_permlane32_swap_b32 %0, %1" : "+v"(a1), "+v"(b1));
        asm volatile("v_permlane32_swap_b32 %0, %1" : "+v"(c1), "+v"(d1));
        union { unsigned u[4]; bf16x8 v; } q; q.u[0] = a1; q.u[1] = c1; q.u[2] = b1; q.u[3] = d1;
        pa1 = q.v;
      }
      if (up) {
#pragma unroll
        for (int r = 0; r < 16; r++) st1[r] = __builtin_amdgcn_exp2f(st1[r]);
        unsigned a2 = cvtpk_bf16(st1[0], st1[1]), c2 = cvtpk_bf16(st1[2], st1[3]);
        unsigned b2 = cvtpk_bf16(st1[4], st1[5]), d2 = cvtpk_bf16(st1[6], st1[7]);
        asm volatile("v_permlane32_swap_b32 %0, %1" : "+v"(a2), "+v"(b2));
        asm volatile("v_permlane32_swap_b32 %0, %1" : "+v"(c2), "+v"(d2));
        union { unsigned u[4]; bf16x8 v; } p; p.u[0] = a2; p.u[1] = c2; p.u[2] = b2; p.u[3] = d2;
        pa2 = p.v;
        unsigned a3 = cvtpk_bf16(st1[8], st1[9]), c3 = cvtpk_bf16(st1[10], st1[11]);
        unsigned b3 = cvtpk_bf16(st1[12], st1[13]), d3 = cvtpk_bf16(st1[14], st1[15]);
        asm volatile("v_permlane32_swap_b32 %0, %1" : "+v"(a3), "+v"(b3));
        asm volatile("v_permlane32_swap_b32 %0, %1" : "+v"(c3), "+v"(d3));
        union { unsigned u[4]; bf16x8 v; } q; q.u[0] = a3; q.u[1] = c3; q.u[2] = b3; q.u[3] = d3;
        pa3 = q.v;
      }

      // ---- l-sum (ones-MFMA, C-layout) + PV ----
      __builtin_amdgcn_s_setprio(1);
      lC = mfma32(pa0, ones, lC);
      lC = mfma32(pa1, ones, lC);
      o0 = mfma32(pa0, vf00, o0);
      o0 = mfma32(pa1, vf01, o0);
      o1 = mfma32(pa0, vf10, o1);
      o1 = mfma32(pa1, vf11, o1);
      if (up) {
        lC = mfma32(pa2, ones, lC);
        lC = mfma32(pa3, ones, lC);
        o0 = mfma32(pa2, vf02, o0);
        o0 = mfma32(pa3, vf03, o0);
        o1 = mfma32(pa2, vf12, o1);
        o1 = mfma32(pa3, vf13, o1);
      }
      __builtin_amdgcn_s_setprio(0);
    }

    // ---- epilogue: divide by l (same C-layout), store bf16 ----
#pragma unroll
    for (int r = 0; r < 16; r++) {
      const int rq = (r & 3) + 8 * (r >> 2) + 4 * hi;
      const int row_g = q0 + wave * 32 + rq;
      const float inv = 1.0f / lC[r];
      short* yp = y + (size_t)(b * T + row_g) * Cc + h * HD;
      yp[l32] = f2b(o0[r] * inv);
      yp[32 + l32] = f2b(o1[r] * inv);
    }
  }
}

extern "C" void kernel_launch(void* const* d_in, const int* in_sizes, int n_in,
                              void* d_out, int out_size, void* d_ws, size_t ws_size,
                              hipStream_t stream) {
  constexpr int B = 4, T = 2048, C = 1024;
  constexpr int M = B * T;          // 8192
  constexpr int N1 = 3 * C;         // 3072
  const float* x      = (const float*)d_in[0];
  const float* w_attn = (const float*)d_in[1];
  const float* w_proj = (const float*)d_in[2];
  float* out = (float*)d_out;

  char* ws = (char*)d_ws;
  short* xb   = (short*)(ws + 0);                       // 16 MB (x bf16; reused as vT)
  short* waT  = (short*)(ws + 16777216);                // 6 MB
  short* wpT  = (short*)(ws + 23068672);                // 2 MB
  short* qkvb = (short*)(ws + 25165824);                // 48 MB
  short* yb   = (short*)(ws + 75497472);                // 16 MB
  short* vT   = xb;                                     // xb dead after qkv GEMM

  const float qscale = 0.125f * 1.44269504088896340736f;  // 1/sqrt(64) * log2(e)

  pre_kernel<<<12288, 256, 0, stream>>>(x, xb, w_attn, waT, w_proj, wpT, qscale);
  gemm8p_kernel<192, short><<<dim3(N1 / 192, M / 256), 512, 0, stream>>>(xb, waT, qkvb, M, N1, C);
  vtrans_kernel<<<dim3(T / 64, B * 16), 256, 0, stream>>>(qkvb, vT);
  attn_kernel<<<dim3(8, B * 16), 256, 0, stream>>>(qkvb, vT, yb);
  gemm8p_kernel<128, float><<<dim3(C / 128, M / 256), 512, 0, stream>>>(yb, wpT, out, M, C, C);
}

// Round 3
// 223.999 us; speedup vs baseline: 1.2127x; 1.0231x over previous
//
#include <hip/hip_runtime.h>
#include <hip/hip_bf16.h>

typedef short bf16x8 __attribute__((ext_vector_type(8)));
typedef short short4v __attribute__((ext_vector_type(4)));
typedef float f32x4 __attribute__((ext_vector_type(4)));
typedef float f32x16 __attribute__((ext_vector_type(16)));

template <bool V> struct BoolC { static constexpr bool value = V; };

__device__ __forceinline__ short f2b(float f) {
  __hip_bfloat16 h = __float2bfloat16(f);
  union { __hip_bfloat16 h; short s; } u; u.h = h; return u.s;
}

// packed f32->bf16 pair (RNE), low = lo, high = hi
__device__ __forceinline__ unsigned cvtpk_bf16(float lo, float hi) {
  unsigned r;
  asm("v_cvt_pk_bf16_f32 %0, %1, %2" : "=v"(r) : "v"(lo), "v"(hi));
  return r;
}

__device__ __forceinline__ f32x16 mfma32(bf16x8 a, bf16x8 b, f32x16 c) {
  return __builtin_amdgcn_mfma_f32_32x32x16_bf16(a, b, c, 0, 0, 0);
}

template <int N> __device__ __forceinline__ void vmwait() {
  if constexpr (N == 0) asm volatile("s_waitcnt vmcnt(0)" ::: "memory");
  else if constexpr (N == 1) asm volatile("s_waitcnt vmcnt(1)" ::: "memory");
  else if constexpr (N == 2) asm volatile("s_waitcnt vmcnt(2)" ::: "memory");
  else if constexpr (N == 3) asm volatile("s_waitcnt vmcnt(3)" ::: "memory");
  else if constexpr (N == 4) asm volatile("s_waitcnt vmcnt(4)" ::: "memory");
  else asm volatile("s_waitcnt vmcnt(5)" ::: "memory");
}

// async 16B global -> LDS DMA (lane i lands at lds_base + i*16; lds ptr wave-uniform)
__device__ __forceinline__ void async_copy16(const short* g, short* l) {
  __builtin_amdgcn_global_load_lds((const __attribute__((address_space(1))) void*)g,
                                   (__attribute__((address_space(3))) void*)l, 16, 0, 0);
}

// ---------------- fused preprocessing: x->bf16, w_attn^T (qscaled), w_proj^T ----------------
__global__ __launch_bounds__(256) void pre_kernel(const float* __restrict__ x, short* __restrict__ xb,
                                                  const float* __restrict__ wa, short* __restrict__ waT,
                                                  const float* __restrict__ wp, short* __restrict__ wpT,
                                                  float qscale) {
  const int tid = threadIdx.x;
  const int blk = blockIdx.x;
  if (blk < 8192) {
    const int i = blk * 256 + tid;
    const float4 v = ((const float4*)x)[i];
    short4v o;
    o[0] = f2b(v.x); o[1] = f2b(v.y); o[2] = f2b(v.z); o[3] = f2b(v.w);
    ((short4v*)xb)[i] = o;
    return;
  }
  __shared__ float t[32][33];
  const float* in; short* out;
  int idx, gxb, Cn, qrows; float qs;
  if (blk < 11264) { idx = blk - 8192;  in = wa; out = waT; gxb = 96; Cn = 3072; qrows = 1024; qs = qscale; }
  else             { idx = blk - 11264; in = wp; out = wpT; gxb = 32; Cn = 1024; qrows = 0;    qs = 1.0f; }
  const int bx = idx % gxb, by = idx / gxb;
  const int tx = tid & 31, ty = tid >> 5;
  const int c0 = bx * 32, r0 = by * 32;
#pragma unroll
  for (int yy = 0; yy < 32; yy += 8)
    t[ty + yy][tx] = in[(size_t)(r0 + ty + yy) * Cn + (c0 + tx)];
  __syncthreads();
#pragma unroll
  for (int yy = 0; yy < 32; yy += 8) {
    const int orow = c0 + ty + yy;
    float v = t[tx][ty + yy];
    if (orow < qrows) v *= qs;
    out[(size_t)orow * 1024 + (r0 + tx)] = f2b(v);
  }
}

// ---------------- V transpose: qkv V-block [b][t][h*64+d] -> vT[(b*16+h)*64+d][t] ----------------
__global__ __launch_bounds__(256) void vtrans_kernel(const short* __restrict__ qkv,
                                                     short* __restrict__ vT) {
  constexpr int T = 2048, C3 = 3072, HD = 64;
  const int bh = blockIdx.y, b = bh >> 4, h = bh & 15;
  const int t0 = blockIdx.x * 64;
  __shared__ short tile[64][72];
  const int tid = threadIdx.x;
  const int tr = tid >> 2, dc = (tid & 3) * 16;
  const short* src = qkv + (size_t)b * T * C3 + (size_t)(t0 + tr) * C3 + 2048 + h * HD + dc;
  *(bf16x8*)&tile[tr][dc] = *(const bf16x8*)src;
  *(bf16x8*)&tile[tr][dc + 8] = *(const bf16x8*)(src + 8);
  __syncthreads();
  const int dr = tid >> 2, tc = (tid & 3) * 16;
  bf16x8 o0, o1;
#pragma unroll
  for (int i = 0; i < 8; i++) o0[i] = tile[tc + i][dr];
#pragma unroll
  for (int i = 0; i < 8; i++) o1[i] = tile[tc + 8 + i][dr];
  short* dst = vT + ((size_t)bh * HD + dr) * T + t0 + tc;
  *(bf16x8*)dst = o0;
  *(bf16x8*)(dst + 8) = o1;
}

// ---------------- C[M,N] = A[M,K] * Bt[N,K]^T — 256xBN tile, read-ahead 4-phase pipeline ----------------
// 512 threads = 8 waves (2 M-halves x 4 N-quarters). BK=64, double-buffered LDS, XOR chunk
// swizzle via inverse-swizzled per-lane global DMA sources (LDS dest linear, as required).
// Phase P: [vmcnt guard publishing A-chunk P+1] -> barrier -> ds_read NEXT phase's A-frags
// (at P3: next tile's B-frags + A0 from buf^1) -> issue 2 stage DMAs -> MFMA on frags read
// LAST phase. LDS read latency hides under a full MFMA cluster + barrier wait; ONE barrier
// per phase (reads after the publish barrier make the second barrier unnecessary).
// Per-wave in-order vmcnt ledger, stream B0..B(NB-1),A0..A3 per tile, 2 issues/phase:
// steady guards {2,3,4,(NB==3?2:3)}; last tile {2,1,0,0}; prologue 3. Never vmcnt(0) in loop.
template <int BN, typename OutT>
__global__ __launch_bounds__(512, 2) void gemm8p_kernel(const short* __restrict__ A,
                                                        const short* __restrict__ Bt,
                                                        OutT* __restrict__ C,
                                                        int M, int N, int K) {
  constexpr int NB = BN / 64;        // B chunks per K-tile == n-frags per wave
  constexpr int NSTREAM = NB + 4;    // loads per tile per wave
  __shared__ short ldsA[2][16384];
  __shared__ short ldsB[2][NB * 4096];

  const int tid = threadIdx.x;
  const int w = tid >> 6, lane = tid & 63;
  const int quad = lane >> 4, l16 = lane & 15;
  const int half = w >> 2;
  const int wn = (w & 3) * (BN / 4);
  const int wm = half * 128;

  const int gx = gridDim.x;
  const int nwg = gx * gridDim.y;
  const int flat = blockIdx.y * gx + blockIdx.x;
  const int swz = (flat & 7) * (nwg >> 3) + (flat >> 3);
  const int bn = swz % gx, bm = swz / gx;
  const int m0 = bm * 256, n0 = bn * BN;

  const int rsub = lane >> 3;                 // 0..7
  const int cl = (lane & 7) ^ rsub;           // logical 16B chunk
  const short* pAsrc = A + (size_t)(m0 + half * 128 + (w & 3) * 8 + rsub) * K + cl * 8;
  const short* pBsrc = Bt + (size_t)(n0 + w * 8 + rsub) * K + cl * 8;
  const int dstoff = w * 512;                 // shorts: wave slice within 8KB chunk

  f32x4 acc[8][NB] = {};
  bf16x8 bfA[NB][2], bfB[NB][2];              // B frags: current / next tile
  bf16x8 afA[2][2], afB[2][2];                // A frags: rotate per phase

  auto issue = [&](int i, int buf, int tt) {
    if (i < NB)
      async_copy16(pBsrc + (size_t)(i * 64) * K + tt * 64, &ldsB[buf][i * 4096 + dstoff]);
    else
      async_copy16(pAsrc + (size_t)((i - NB) * 32) * K + tt * 64,
                   &ldsA[buf][(i - NB) * 4096 + dstoff]);
  };
  auto readA = [&](bf16x8 (&dst)[2][2], int buf, int chunk) {
#pragma unroll
    for (int mm = 0; mm < 2; ++mm)
#pragma unroll
      for (int kh = 0; kh < 2; ++kh)
        dst[mm][kh] = *(const bf16x8*)&ldsA[buf][((chunk * 2 + half) * 32 + mm * 16 + l16) * 64 +
                                                 (((kh * 4 + quad) ^ (l16 & 7)) * 8)];
  };
  auto readB = [&](bf16x8 (&dst)[NB][2], int buf) {
#pragma unroll
    for (int nf = 0; nf < NB; ++nf)
#pragma unroll
      for (int kh = 0; kh < 2; ++kh)
        dst[nf][kh] = *(const bf16x8*)&ldsB[buf][(wn + nf * 16 + l16) * 64 +
                                                 (((kh * 4 + quad) ^ (l16 & 7)) * 8)];
  };

#define MFMA_CL(P, AF, BF)                                                                     \
  __builtin_amdgcn_s_setprio(1);                                                               \
  _Pragma("unroll") for (int mm = 0; mm < 2; ++mm)                                             \
  _Pragma("unroll") for (int nf = 0; nf < NB; ++nf) {                                          \
    acc[(P)*2 + mm][nf] = __builtin_amdgcn_mfma_f32_16x16x32_bf16((AF)[mm][0], (BF)[nf][0],    \
                                                                  acc[(P)*2 + mm][nf], 0, 0, 0); \
    acc[(P)*2 + mm][nf] = __builtin_amdgcn_mfma_f32_16x16x32_bf16((AF)[mm][1], (BF)[nf][1],    \
                                                                  acc[(P)*2 + mm][nf], 0, 0, 0); \
  }                                                                                            \
  __builtin_amdgcn_s_setprio(0);

  // prologue: stage tile 0 into buf 0; publish B + A0; pre-read bfr + af0
#pragma unroll
  for (int i = 0; i < NSTREAM; ++i) issue(i, 0, 0);
  vmwait<3>();
  __builtin_amdgcn_s_barrier();
  readB(bfA, 0);
  readA(afA, 0, 0);

  auto tileb = [&](int buf, auto lastc, int tnext, auto& bfc, auto& bfn) {
    constexpr bool LASTT = decltype(lastc)::value;
    constexpr int g1 = LASTT ? 1 : 3;
    constexpr int g2 = LASTT ? 0 : 4;
    constexpr int g3 = LASTT ? 0 : (NB == 3 ? 2 : 3);
    // phase 0: publish A1; read af1; MFMA af0
    vmwait<2>();
    __builtin_amdgcn_s_barrier();
    readA(afB, buf, 1);
    if constexpr (!LASTT) { issue(0, buf ^ 1, tnext); issue(1, buf ^ 1, tnext); }
    MFMA_CL(0, afA, bfc)
    // phase 1: publish A2; read af2; MFMA af1
    vmwait<g1>();
    __builtin_amdgcn_s_barrier();
    readA(afA, buf, 2);
    if constexpr (!LASTT) { issue(2, buf ^ 1, tnext); issue(3, buf ^ 1, tnext); }
    MFMA_CL(1, afB, bfc)
    // phase 2: publish A3; read af3; MFMA af2
    vmwait<g2>();
    __builtin_amdgcn_s_barrier();
    readA(afB, buf, 3);
    if constexpr (!LASTT) { issue(4, buf ^ 1, tnext); issue(5, buf ^ 1, tnext); }
    MFMA_CL(2, afA, bfc)
    // phase 3: publish next tile's B + A0; read bfr',af0' from buf^1; MFMA af3
    vmwait<g3>();
    __builtin_amdgcn_s_barrier();
    if constexpr (!LASTT) {
      readB(bfn, buf ^ 1);
      readA(afA, buf ^ 1, 0);
      if constexpr (6 < NSTREAM) issue(6, buf ^ 1, tnext);
    }
    MFMA_CL(3, afB, bfc)
  };

  const int NT = K >> 6;  // assumed even (K=1024 -> 16)
  for (int t = 0; t < NT - 2; t += 2) {
    tileb(0, BoolC<false>{}, t + 1, bfA, bfB);
    tileb(1, BoolC<false>{}, t + 2, bfB, bfA);
  }
  tileb(0, BoolC<false>{}, NT - 1, bfA, bfB);
  tileb(1, BoolC<true>{}, 0, bfB, bfA);
#undef MFMA_CL

  (void)M;
#pragma unroll
  for (int mf = 0; mf < 8; ++mf)
#pragma unroll
    for (int nf = 0; nf < NB; ++nf) {
      const int col = n0 + wn + nf * 16 + l16;
#pragma unroll
      for (int r = 0; r < 4; ++r) {
        const int row = m0 + wm + mf * 16 + quad * 4 + r;
        if constexpr (sizeof(OutT) == 4)
          C[(size_t)row * N + col] = acc[mf][nf][r];
        else
          C[(size_t)row * N + col] = f2b(acc[mf][nf][r]);
      }
    }
}

// ---------------- causal flash attention: 32x32 swapped-QK^T, in-register softmax ----------------
__global__ __launch_bounds__(256, 2) void attn_kernel(const short* __restrict__ qkv,
                                                      const short* __restrict__ vT,
                                                      short* __restrict__ y) {
  constexpr int T = 2048, C3 = 3072, Cc = 1024, HD = 64;
  const int f = blockIdx.y * 8 + blockIdx.x;
  const int bh = (f & 7) * 8 + ((f >> 3) & 7);
  const int xb = f >> 6;
  const int b = bh >> 4, h = bh & 15;
  const int tid = threadIdx.x, lane = tid & 63, wave = tid >> 6;
  const int l32 = lane & 31, hi = lane >> 5;

  __shared__ short Ksb[2][64 * 64];    // [buf][kv][d], XOR-swizzled 16B chunks
  __shared__ short Vtb[2][64 * 64];    // [buf][d][kv], XOR-swizzled 16B chunks

  const size_t base = (size_t)b * T * C3;
  const int qcol = h * HD, kcol = Cc + h * HD;
  const size_t vtbase = (size_t)bh * HD * T;

  const int r8 = lane >> 3;
  const int cg8 = ((lane & 7) ^ r8) * 8;
  const short* gk[2];
  const short* gv[2];
  short* lk[2][2]; short* lv[2][2];
#pragma unroll
  for (int t8 = 0; t8 < 2; t8++) {
    const int row = wave * 16 + t8 * 8 + r8;
    gk[t8] = qkv + base + (size_t)row * C3 + kcol + cg8;
    gv[t8] = vT + vtbase + (size_t)row * T + cg8;
#pragma unroll
    for (int bu = 0; bu < 2; bu++) {
      lk[bu][t8] = &Ksb[bu][(wave * 16 + t8 * 8) * 64];
      lv[bu][t8] = &Vtb[bu][(wave * 16 + t8 * 8) * 64];
    }
  }
  const int rs7 = l32 & 7;  // frag-read row parity for chunk XOR

  bf16x8 ones;
#pragma unroll
  for (int i = 0; i < 8; i++) ones[i] = (short)0x3F80;  // bf16 1.0

  for (int half = 0; half < 2; half++) {
    const int t = half ? xb : (15 - xb);
    const int q0 = t * 128;
    const int jmax = 2 * t + 1;
    const int jd = 2 * t + (wave >> 1);       // this wave's diagonal KV-tile
    const int qrow = q0 + wave * 32 + l32;    // this lane's q (S^T col)

    bf16x8 qf[4];
    {
      const short* qp = qkv + base + (size_t)qrow * C3 + qcol + hi * 8;
#pragma unroll
      for (int wk = 0; wk < 4; wk++) qf[wk] = *(const bf16x8*)(qp + wk * 16);
    }

    f32x16 o0 = {}, o1 = {}, lC = {};

    async_copy16(gk[0], lk[0][0]);
    async_copy16(gk[1], lk[0][1]);
    async_copy16(gv[0], lv[0][0]);
    async_copy16(gv[1], lv[0][1]);

    for (int j = 0; j <= jmax; j++) {
      const int cur = j & 1;
      __syncthreads();  // drains vmcnt: tile j staged in buf[cur]

      if (j < jmax) {
        const size_t ko = (size_t)(j + 1) * 64 * C3;
        const int vo = (j + 1) * 64;
        async_copy16(gk[0] + ko, lk[cur ^ 1][0]);
        async_copy16(gk[1] + ko, lk[cur ^ 1][1]);
        async_copy16(gv[0] + vo, lv[cur ^ 1][0]);
        async_copy16(gv[1] + vo, lv[cur ^ 1][1]);
      }

      if (j > jd) continue;  // fully-masked tile for this wave (barriers above still uniform)

      const bool up = (64 * j + 32) <= (q0 + wave * 32 + 31);

      // ---- QK^T (swapped): st = K-tile x Q^T, col=q, row=kv ----
      f32x16 st0 = {}, st1 = {};
      __builtin_amdgcn_s_setprio(1);
#pragma unroll
      for (int wk = 0; wk < 4; wk++) {
        const bf16x8 k0 = *(const bf16x8*)&Ksb[cur][l32 * 64 + (((2 * wk + hi) ^ rs7) * 8)];
        st0 = mfma32(k0, qf[wk], st0);
      }
      if (up) {
#pragma unroll
        for (int wk = 0; wk < 4; wk++) {
          const bf16x8 k1 = *(const bf16x8*)&Ksb[cur][(32 + l32) * 64 + (((2 * wk + hi) ^ rs7) * 8)];
          st1 = mfma32(k1, qf[wk], st1);
        }
      }
      __builtin_amdgcn_s_setprio(0);

      // ---- causal mask on diagonal tile ----
      if (j == jd) {
#pragma unroll
        for (int r = 0; r < 16; r++) {
          const int kvl = 64 * j + (r & 3) + 8 * (r >> 2) + 4 * hi;
          if (kvl > qrow) st0[r] = -INFINITY;
          if (up && (kvl + 32 > qrow)) st1[r] = -INFINITY;
        }
      }

      // ---- V B-frags (kv-windows 0,1 always; 2,3 only if up) ----
      bf16x8 vf00, vf01, vf10, vf11, vf02, vf03, vf12, vf13;
      vf00 = *(const bf16x8*)&Vtb[cur][l32 * 64 + (((0 + hi) ^ rs7) * 8)];
      vf01 = *(const bf16x8*)&Vtb[cur][l32 * 64 + (((2 + hi) ^ rs7) * 8)];
      vf10 = *(const bf16x8*)&Vtb[cur][(32 + l32) * 64 + (((0 + hi) ^ rs7) * 8)];
      vf11 = *(const bf16x8*)&Vtb[cur][(32 + l32) * 64 + (((2 + hi) ^ rs7) * 8)];
      if (up) {
        vf02 = *(const bf16x8*)&Vtb[cur][l32 * 64 + (((4 + hi) ^ rs7) * 8)];
        vf03 = *(const bf16x8*)&Vtb[cur][l32 * 64 + (((6 + hi) ^ rs7) * 8)];
        vf12 = *(const bf16x8*)&Vtb[cur][(32 + l32) * 64 + (((4 + hi) ^ rs7) * 8)];
        vf13 = *(const bf16x8*)&Vtb[cur][(32 + l32) * 64 + (((6 + hi) ^ rs7) * 8)];
      }

      // ---- exp2 in-place, pack P->bf16 A-frags via cvt_pk + permlane32_swap ----
#pragma unroll
      for (int r = 0; r < 16; r++) st0[r] = __builtin_amdgcn_exp2f(st0[r]);
      bf16x8 pa0, pa1, pa2, pa3;
      {
        unsigned a0 = cvtpk_bf16(st0[0], st0[1]), c0 = cvtpk_bf16(st0[2], st0[3]);
        unsigned b0 = cvtpk_bf16(st0[4], st0[5]), d0 = cvtpk_bf16(st0[6], st0[7]);
        asm volatile("v_permlane32_swap_b32 %0, %1" : "+v"(a0), "+v"(b0));
        asm volatile("v_permlane32_swap_b32 %0, %1" : "+v"(c0), "+v"(d0));
        union { unsigned u[4]; bf16x8 v; } p; p.u[0] = a0; p.u[1] = c0; p.u[2] = b0; p.u[3] = d0;
        pa0 = p.v;
        unsigned a1 = cvtpk_bf16(st0[8], st0[9]), c1 = cvtpk_bf16(st0[10], st0[11]);
        unsigned b1 = cvtpk_bf16(st0[12], st0[13]), d1 = cvtpk_bf16(st0[14], st0[15]);
        asm volatile("v_permlane32_swap_b32 %0, %1" : "+v"(a1), "+v"(b1));
        asm volatile("v_permlane32_swap_b32 %0, %1" : "+v"(c1), "+v"(d1));
        union { unsigned u[4]; bf16x8 v; } q; q.u[0] = a1; q.u[1] = c1; q.u[2] = b1; q.u[3] = d1;
        pa1 = q.v;
      }
      if (up) {
#pragma unroll
        for (int r = 0; r < 16; r++) st1[r] = __builtin_amdgcn_exp2f(st1[r]);
        unsigned a2 = cvtpk_bf16(st1[0], st1[1]), c2 = cvtpk_bf16(st1[2], st1[3]);
        unsigned b2 = cvtpk_bf16(st1[4], st1[5]), d2 = cvtpk_bf16(st1[6], st1[7]);
        asm volatile("v_permlane32_swap_b32 %0, %1" : "+v"(a2), "+v"(b2));
        asm volatile("v_permlane32_swap_b32 %0, %1" : "+v"(c2), "+v"(d2));
        union { unsigned u[4]; bf16x8 v; } p; p.u[0] = a2; p.u[1] = c2; p.u[2] = b2; p.u[3] = d2;
        pa2 = p.v;
        unsigned a3 = cvtpk_bf16(st1[8], st1[9]), c3 = cvtpk_bf16(st1[10], st1[11]);
        unsigned b3 = cvtpk_bf16(st1[12], st1[13]), d3 = cvtpk_bf16(st1[14], st1[15]);
        asm volatile("v_permlane32_swap_b32 %0, %1" : "+v"(a3), "+v"(b3));
        asm volatile("v_permlane32_swap_b32 %0, %1" : "+v"(c3), "+v"(d3));
        union { unsigned u[4]; bf16x8 v; } q; q.u[0] = a3; q.u[1] = c3; q.u[2] = b3; q.u[3] = d3;
        pa3 = q.v;
      }

      // ---- l-sum (ones-MFMA, C-layout) + PV ----
      __builtin_amdgcn_s_setprio(1);
      lC = mfma32(pa0, ones, lC);
      lC = mfma32(pa1, ones, lC);
      o0 = mfma32(pa0, vf00, o0);
      o0 = mfma32(pa1, vf01, o0);
      o1 = mfma32(pa0, vf10, o1);
      o1 = mfma32(pa1, vf11, o1);
      if (up) {
        lC = mfma32(pa2, ones, lC);
        lC = mfma32(pa3, ones, lC);
        o0 = mfma32(pa2, vf02, o0);
        o0 = mfma32(pa3, vf03, o0);
        o1 = mfma32(pa2, vf12, o1);
        o1 = mfma32(pa3, vf13, o1);
      }
      __builtin_amdgcn_s_setprio(0);
    }

    // ---- epilogue: divide by l (same C-layout), store bf16 ----
#pragma unroll
    for (int r = 0; r < 16; r++) {
      const int rq = (r & 3) + 8 * (r >> 2) + 4 * hi;
      const int row_g = q0 + wave * 32 + rq;
      const float inv = 1.0f / lC[r];
      short* yp = y + (size_t)(b * T + row_g) * Cc + h * HD;
      yp[l32] = f2b(o0[r] * inv);
      yp[32 + l32] = f2b(o1[r] * inv);
    }
  }
}

extern "C" void kernel_launch(void* const* d_in, const int* in_sizes, int n_in,
                              void* d_out, int out_size, void* d_ws, size_t ws_size,
                              hipStream_t stream) {
  constexpr int B = 4, T = 2048, C = 1024;
  constexpr int M = B * T;          // 8192
  constexpr int N1 = 3 * C;         // 3072
  const float* x      = (const float*)d_in[0];
  const float* w_attn = (const float*)d_in[1];
  const float* w_proj = (const float*)d_in[2];
  float* out = (float*)d_out;

  char* ws = (char*)d_ws;
  short* xb   = (short*)(ws + 0);                       // 16 MB (x bf16; reused as vT)
  short* waT  = (short*)(ws + 16777216);                // 6 MB
  short* wpT  = (short*)(ws + 23068672);                // 2 MB
  short* qkvb = (short*)(ws + 25165824);                // 48 MB
  short* yb   = (short*)(ws + 75497472);                // 16 MB
  short* vT   = xb;                                     // xb dead after qkv GEMM

  const float qscale = 0.125f * 1.44269504088896340736f;  // 1/sqrt(64) * log2(e)

  pre_kernel<<<12288, 256, 0, stream>>>(x, xb, w_attn, waT, w_proj, wpT, qscale);
  gemm8p_kernel<192, short><<<dim3(N1 / 192, M / 256), 512, 0, stream>>>(xb, waT, qkvb, M, N1, C);
  vtrans_kernel<<<dim3(T / 64, B * 16), 256, 0, stream>>>(qkvb, vT);
  attn_kernel<<<dim3(8, B * 16), 256, 0, stream>>>(qkvb, vT, yb);
  gemm8p_kernel<128, float><<<dim3(C / 128, M / 256), 512, 0, stream>>>(yb, wpT, out, M, C, C);
}